// Round 5
// baseline (374.386 us; speedup 1.0000x reference)
//
#include <hip/hip_runtime.h>
#include <hip/hip_bf16.h>
#include <cstdint>
#include <cstddef>

#define GS     128
#define OBS    1024
#define HSZ    256
#define OUTSZ  1024
#define NOUT   18
#define BATCH  256

typedef short  short8  __attribute__((ext_vector_type(8)));
typedef float  f32x4   __attribute__((ext_vector_type(4)));

__device__ __forceinline__ uint32_t f2bf_bits(float f) {
  uint32_t u = __builtin_bit_cast(uint32_t, f);
  return (u + 0x7fffu + ((u >> 16) & 1u)) >> 16;
}
__device__ __forceinline__ float bf_bits2f(uint32_t b) {
  return __builtin_bit_cast(float, b << 16);
}
__device__ __forceinline__ uint4 cvt8s(const float4 a, const float4 b) {
  float v[8] = {a.x, a.y, a.z, a.w, b.x, b.y, b.z, b.w};
  uint32_t h[8];
#pragma unroll
  for (int e = 0; e < 8; ++e) h[e] = f2bf_bits(v[e]);
  return make_uint4(h[0] | (h[1] << 16), h[2] | (h[3] << 16),
                    h[4] | (h[5] << 16), h[6] | (h[7] << 16));
}

// ---------------------------------------------------------------------------
// P0 (merged preps):
//   blk <128 : W0cat [1024][512] fp32 -> Wt [512][1024] bf16 (transposed)
//   blk>=128 : WlT[19][1024]: rows 0..17 = Wl^T, row 18 = Wv
// ---------------------------------------------------------------------------
__global__ __launch_bounds__(256) void prep_kernel(
    const float* __restrict__ W0_rel, const float* __restrict__ W0_root,
    ushort* __restrict__ Wt, const float* __restrict__ Wl,
    const float* __restrict__ Wv, float* __restrict__ WlT)
{
  __shared__ float T[64][65];
  const int blk = blockIdx.x;
  const int t = threadIdx.x;
  if (blk < 128) {
    const int k0 = (blk & 15) * 64;
    const int n0 = (blk >> 4) * 64;
    for (int idx = t; idx < 4096; idx += 256) {
      const int r = idx >> 6, c = idx & 63;
      const int n = n0 + c;
      T[r][c] = (n < HSZ) ? W0_rel[(size_t)(k0 + r) * HSZ + n]
                          : W0_root[(size_t)(k0 + r) * HSZ + (n - HSZ)];
    }
    __syncthreads();
    for (int idx = t; idx < 4096; idx += 256) {
      const int r = idx >> 6, c = idx & 63;
      Wt[(size_t)(n0 + r) * OBS + (k0 + c)] = (ushort)f2bf_bits(T[c][r]);
    }
  } else {
    const int o = (blk - 128) * 256 + t;
#pragma unroll
    for (int c = 0; c < NOUT; ++c)
      WlT[(size_t)c * OUTSZ + o] = Wl[(size_t)o * NOUT + c];
    WlT[(size_t)18 * OUTSZ + o] = Wv[o];
  }
}

// ---------------------------------------------------------------------------
// K1: YT[b][h][k] bf16  (h in [0,256), k in [0,256)):
//   k<128 : YT[b][h][k]     = (x @ W0_rel)^T [h][k]   (node k)
//   k>=128: YT[b][h][128+j] = (x @ W0_root)^T [h][j]  (node j)
// Grid (2, BATCH): block owns 64 node-rows x ALL 512 cat-cols.
// nodes read ONCE; fp32->bf16 cvt ONCE. BK=32, 2 blocks/CU (46 KB LDS).
// Transposed D comes free by swapping MFMA operands.
// ---------------------------------------------------------------------------
__global__ __launch_bounds__(256, 2) void gemm0_mfma(
    const float* __restrict__ flat, const float* __restrict__ nodes,
    const int* __restrict__ num_nodes, const ushort* __restrict__ Wt,
    ushort* __restrict__ YT)
{
  __shared__ ushort As[64][40];    // [node-row][k] (+8 pad)
  __shared__ ushort Bs[512][40];   // [cat-col][k]  (+8 pad)

  const int mh = blockIdx.x;       // node-row half
  const int b  = blockIdx.y;
  const int nb = num_nodes[b];
  const int t  = threadIdx.x;

  // A staging: row = t>>2 (0..63), 8 k's at (t&3)*8
  const int arow = t >> 2;
  const int akb  = (t & 3) * 8;
  const int g = mh * 64 + arow;
  const float* xsrc = ((g == nb) ? (flat + (size_t)b * OBS)
                                 : (nodes + ((size_t)b * GS + g) * OBS)) + akb;
  // B staging: rows t and t+256, 32 ushorts each per K-step
  const ushort* wsrc0 = Wt + (size_t)t * OBS;
  const ushort* wsrc1 = Wt + (size_t)(t + 256) * OBS;

  const int wv = t >> 6;           // wave owns cat-cols [wv*128, wv*128+128)
  const int lane = t & 63;
  const int ln = lane & 15, q = lane >> 4;

  f32x4 acc[8][4] = {};            // [h-tile jj][node-tile ii]

  float4 pa0 = *(const float4*)(xsrc);
  float4 pa1 = *(const float4*)(xsrc + 4);

  for (int ks = 0; ks < 32; ++ks) {
    const int kk = ks * 32;
    *(uint4*)&As[arow][akb] = cvt8s(pa0, pa1);
    {
      const uint4 w0 = *(const uint4*)(wsrc0 + kk);
      const uint4 w1 = *(const uint4*)(wsrc0 + kk + 8);
      const uint4 w2 = *(const uint4*)(wsrc0 + kk + 16);
      const uint4 w3 = *(const uint4*)(wsrc0 + kk + 24);
      const uint4 w4 = *(const uint4*)(wsrc1 + kk);
      const uint4 w5 = *(const uint4*)(wsrc1 + kk + 8);
      const uint4 w6 = *(const uint4*)(wsrc1 + kk + 16);
      const uint4 w7 = *(const uint4*)(wsrc1 + kk + 24);
      *(uint4*)&Bs[t][0]        = w0; *(uint4*)&Bs[t][8]        = w1;
      *(uint4*)&Bs[t][16]       = w2; *(uint4*)&Bs[t][24]       = w3;
      *(uint4*)&Bs[t + 256][0]  = w4; *(uint4*)&Bs[t + 256][8]  = w5;
      *(uint4*)&Bs[t + 256][16] = w6; *(uint4*)&Bs[t + 256][24] = w7;
    }
    __syncthreads();

    if (ks < 31) {                 // prefetch next A slice (HBM stream)
      pa0 = *(const float4*)(xsrc + kk + 32);
      pa1 = *(const float4*)(xsrc + kk + 36);
    }

    short8 ah[4], bh[8];
#pragma unroll
    for (int ii = 0; ii < 4; ++ii)
      ah[ii] = *(const short8*)&As[ii * 16 + ln][q * 8];
#pragma unroll
    for (int jj = 0; jj < 8; ++jj)
      bh[jj] = *(const short8*)&Bs[wv * 128 + jj * 16 + ln][q * 8];
#pragma unroll
    for (int jj = 0; jj < 8; ++jj)
#pragma unroll
      for (int ii = 0; ii < 4; ++ii)
        acc[jj][ii] = __builtin_amdgcn_mfma_f32_16x16x32_bf16(
            bh[jj], ah[ii], acc[jj][ii], 0, 0, 0);   // swapped => D[h'][node]
    __syncthreads();
  }

  // D row = cat-col h' (q*4+r within 16), D col = node (ln within 16)
#pragma unroll
  for (int jj = 0; jj < 8; ++jj) {
    const int hp = wv * 128 + jj * 16 + q * 4;     // uniform side per jj/wv
    const int kofs = (hp < 256) ? 0 : 128;
#pragma unroll
    for (int ii = 0; ii < 4; ++ii) {
      const int kidx = kofs + mh * 64 + ii * 16 + ln;
#pragma unroll
      for (int r = 0; r < 4; ++r) {
        const int h2 = (hp + r) & 255;
        YT[((size_t)b * 256 + h2) * 256 + kidx] =
            (ushort)f2bf_bits(acc[jj][ii][r]);
      }
    }
  }
}

// ---------------------------------------------------------------------------
// K2 (per batch): masks -> MFMA P=[A^T|I]@YT -> relu/masked-sum epilogue.
//   Z[b][h]     = aggr1[h] = sum_{j in S} relu(b0+P[j][h])
//   Z[b][256+h] = h0n[h]   = relu(b0+P[n][h])
// ---------------------------------------------------------------------------
__global__ __launch_bounds__(256) void fused_aggr(
    const ushort* __restrict__ YT, const int* __restrict__ adj,
    const int* __restrict__ num_nodes, const float* __restrict__ b0,
    float* __restrict__ Z)
{
  __shared__ ushort   Ys[256][264];     // 132 KB
  __shared__ uint32_t rm[128][4];
  __shared__ uint32_t cmL[128][4];
  __shared__ float    redq[4][4][64];

  const int b = blockIdx.x;
  const int n = num_nodes[b];
  const int t = threadIdx.x;
  const int wv = t >> 6, lane = t & 63;
  const int ln = lane & 15, q = lane >> 4;

  // stage YT[b] -> LDS (issue early)
  for (int it = 0; it < 32; ++it) {
    const int id = t + it * 256;
    const int row = id >> 5, c8 = (id & 31) * 8;
    *(uint4*)&Ys[row][c8] = *(const uint4*)&YT[((size_t)b * 256 + row) * 256 + c8];
  }

  // masks
#pragma unroll 4
  for (int i = 0; i < 32; ++i) {
    const int k = wv * 32 + i;
    const int* arow = adj + ((size_t)b * GS + k) * GS;
    const unsigned long long m0 = __ballot(arow[lane] != 0);
    const unsigned long long m1 = __ballot(arow[64 + lane] != 0);
    if (lane == 0) {
      rm[k][0] = (uint32_t)m0; rm[k][1] = (uint32_t)(m0 >> 32);
      rm[k][2] = (uint32_t)m1; rm[k][3] = (uint32_t)(m1 >> 32);
    }
  }
  __syncthreads();
  if (t < 128) {
    uint32_t c0 = 0, c1 = 0, c2 = 0, c3 = 0;
    const int w = t >> 5, sh = t & 31;
#pragma unroll 8
    for (int k = 0; k < 128; ++k) {
      const uint32_t bit = (rm[k][w] >> sh) & 1u;
      if (k < 32)      c0 |= bit << k;
      else if (k < 64) c1 |= bit << (k - 32);
      else if (k < 96) c2 |= bit << (k - 64);
      else             c3 |= bit << (k - 96);
    }
    cmL[t][0] = c0; cmL[t][1] = c1; cmL[t][2] = c2; cmL[t][3] = c3;
  }
  __syncthreads();
  if (t == 0) {
    cmL[n][n >> 5] |= 1u << (n & 31);
    if (n > 0) {
      cmL[n - 1][n >> 5] |= 1u << (n & 31);
      cmL[n][(n - 1) >> 5] |= 1u << ((n - 1) & 31);
    }
  }
  __syncthreads();

  // MFMA: wave wv owns h in [wv*64, wv*64+64)
  f32x4 acc[8][4] = {};
  for (int ks = 0; ks < 8; ++ks) {
    short8 bf[4];
#pragma unroll
    for (int ht = 0; ht < 4; ++ht)
      bf[ht] = *(const short8*)&Ys[wv * 64 + ht * 16 + ln][ks * 32 + q * 8];
#pragma unroll
    for (int jt = 0; jt < 8; ++jt) {
      short8 af;
      if (ks < 4) {
        const uint32_t w = cmL[jt * 16 + ln][ks];
        const uint32_t byte = (w >> (q * 8)) & 0xFFu;
#pragma unroll
        for (int i = 0; i < 8; ++i)
          af[i] = (short)(((byte >> i) & 1u) ? 0x3F80 : 0);
      } else {
        const int base = (ks - 4) * 32 + q * 8;
        const int j = jt * 16 + ln;
#pragma unroll
        for (int i = 0; i < 8; ++i)
          af[i] = (short)((j == base + i) ? 0x3F80 : 0);
      }
#pragma unroll
      for (int ht = 0; ht < 4; ++ht)
        acc[jt][ht] = __builtin_amdgcn_mfma_f32_16x16x32_bf16(
            af, bf[ht], acc[jt][ht], 0, 0, 0);
    }
  }

  // epilogue
  const uint32_t S0 = cmL[n][0], S1 = cmL[n][1], S2 = cmL[n][2], S3 = cmL[n][3];
  float bb[4];
#pragma unroll
  for (int ht = 0; ht < 4; ++ht) bb[ht] = b0[wv * 64 + ht * 16 + ln];

  float asum[4] = {0.f, 0.f, 0.f, 0.f};
#pragma unroll
  for (int jt = 0; jt < 8; ++jt)
#pragma unroll
    for (int r = 0; r < 4; ++r) {
      const int j = jt * 16 + q * 4 + r;
      const uint32_t Sw = (j < 32) ? S0 : (j < 64) ? S1 : (j < 96) ? S2 : S3;
      const bool sj = (Sw >> (j & 31)) & 1u;
      const bool isn = (j == n);
#pragma unroll
      for (int ht = 0; ht < 4; ++ht) {
        const float v = fmaxf(bb[ht] + acc[jt][ht][r], 0.f);
        if (sj) asum[ht] += v;
        if (isn) Z[(size_t)b * 512 + 256 + wv * 64 + ht * 16 + ln] = v;
      }
    }
#pragma unroll
  for (int ht = 0; ht < 4; ++ht) redq[wv][q][ht * 16 + ln] = asum[ht];
  __syncthreads();
  {
    const int hl = t & 63, w2 = t >> 6;
    Z[(size_t)b * 512 + w2 * 64 + hl] =
        redq[w2][0][hl] + redq[w2][1][hl] + redq[w2][2][hl] + redq[w2][3][hl];
  }
}

// ---------------------------------------------------------------------------
// K3: h1[256][1024] = relu(Z @ [W1_rel ; W1_root] + b1)   (fp32 tiled GEMM)
// ---------------------------------------------------------------------------
__global__ __launch_bounds__(256) void gemm1_kernel(
    const float* __restrict__ Z, const float* __restrict__ W1_rel,
    const float* __restrict__ W1_root, const float* __restrict__ b1,
    float* __restrict__ h1)
{
  __shared__ float As2[16][64];
  __shared__ float Bs2[16][64];

  const int n0 = blockIdx.x * 64;
  const int m0 = blockIdx.y * 64;
  const int t = threadIdx.x;
  const int tx = t & 15, ty = t >> 4;
  const int arow = t >> 2, acol4 = (t & 3) * 4;
  const int brow = t >> 4, bcol4 = (t & 15) * 4;

  float acc[4][4] = {};

  for (int kk = 0; kk < 512; kk += 16) {
    const float4 av = *(const float4*)&Z[(size_t)(m0 + arow) * 512 + kk + acol4];
    const int k = kk + brow;
    const float* Bp = (k < HSZ) ? (W1_rel + (size_t)k * OUTSZ)
                                : (W1_root + (size_t)(k - HSZ) * OUTSZ);
    const float4 bv = *(const float4*)(Bp + n0 + bcol4);
    As2[acol4 + 0][arow] = av.x;
    As2[acol4 + 1][arow] = av.y;
    As2[acol4 + 2][arow] = av.z;
    As2[acol4 + 3][arow] = av.w;
    *(float4*)&Bs2[brow][bcol4] = bv;
    __syncthreads();
#pragma unroll
    for (int k2 = 0; k2 < 16; ++k2) {
      const float4 a = *(const float4*)&As2[k2][ty * 4];
      const float4 qv = *(const float4*)&Bs2[k2][tx * 4];
      const float af[4] = {a.x, a.y, a.z, a.w};
      const float qf[4] = {qv.x, qv.y, qv.z, qv.w};
#pragma unroll
      for (int i = 0; i < 4; ++i)
#pragma unroll
        for (int j = 0; j < 4; ++j)
          acc[i][j] = fmaf(af[i], qf[j], acc[i][j]);
    }
    __syncthreads();
  }

#pragma unroll
  for (int i = 0; i < 4; ++i) {
    const int row = m0 + ty * 4 + i;
    const int colb = n0 + tx * 4;
    float4 st;
    st.x = fmaxf(acc[i][0] + b1[colb + 0], 0.f);
    st.y = fmaxf(acc[i][1] + b1[colb + 1], 0.f);
    st.z = fmaxf(acc[i][2] + b1[colb + 2], 0.f);
    st.w = fmaxf(acc[i][3] + b1[colb + 3], 0.f);
    *(float4*)&h1[(size_t)row * OUTSZ + colb] = st;
  }
}

// ---------------------------------------------------------------------------
// K4: per batch: logits = h1 @ Wl + bl ; value = h1 @ Wv + bv  (via WlT)
// ---------------------------------------------------------------------------
__global__ __launch_bounds__(256) void head_kernel(
    const float* __restrict__ h1, const float* __restrict__ WlT,
    const float* __restrict__ bl, const float* __restrict__ bv,
    float* __restrict__ out)
{
  __shared__ float pl[19][4];
  const int b = blockIdx.x;
  const int t = threadIdx.x;
  const int wv = t >> 6, lane = t & 63;
  const int o4 = t * 4;

  const float4 hv = *(const float4*)&h1[(size_t)b * OUTSZ + o4];
  float p[19];
#pragma unroll
  for (int c = 0; c < 19; ++c) {
    const float4 w = *(const float4*)&WlT[(size_t)c * OUTSZ + o4];
    p[c] = hv.x * w.x + hv.y * w.y + hv.z * w.z + hv.w * w.w;
  }
#pragma unroll
  for (int c = 0; c < 19; ++c) {
    float v = p[c];
    v += __shfl_down(v, 32); v += __shfl_down(v, 16);
    v += __shfl_down(v, 8);  v += __shfl_down(v, 4);
    v += __shfl_down(v, 2);  v += __shfl_down(v, 1);
    if (lane == 0) pl[c][wv] = v;
  }
  __syncthreads();
  if (t < 19) {
    const float s = pl[t][0] + pl[t][1] + pl[t][2] + pl[t][3];
    if (t < NOUT) out[(size_t)b * NOUT + t] = s + bl[t];
    else          out[(size_t)BATCH * NOUT + b] = s + bv[0];
  }
}

// ---------------------------------------------------------------------------
extern "C" void kernel_launch(void* const* d_in, const int* in_sizes, int n_in,
                              void* d_out, int out_size, void* d_ws, size_t ws_size,
                              hipStream_t stream)
{
  const float* flat      = (const float*)d_in[0];
  const float* nodes     = (const float*)d_in[1];
  const int*   num_nodes = (const int*)  d_in[2];
  const int*   adj       = (const int*)  d_in[3];
  const float* W0_rel    = (const float*)d_in[5];
  const float* b0        = (const float*)d_in[6];
  const float* W0_root   = (const float*)d_in[7];
  const float* W1_rel    = (const float*)d_in[8];
  const float* b1        = (const float*)d_in[9];
  const float* W1_root   = (const float*)d_in[10];
  const float* Wl        = (const float*)d_in[11];
  const float* bl        = (const float*)d_in[12];
  const float* Wv        = (const float*)d_in[13];
  const float* bv        = (const float*)d_in[14];
  float* out = (float*)d_out;

  char* ws = (char*)d_ws;
  ushort* YT  = (ushort*)ws;   ws += (size_t)BATCH * 256 * 256 * 2;  // 32 MiB
  ushort* Wt  = (ushort*)ws;   ws += (size_t)512 * OBS * 2;          // 1 MiB
  float*  WlT = (float*)ws;    ws += (size_t)19 * OUTSZ * 4;         // 76 KiB
  float*  Z   = (float*)ws;    ws += (size_t)BATCH * 512 * 4;        // 512 KiB
  float*  h1  = (float*)ws;    ws += (size_t)BATCH * OUTSZ * 4;      // 1 MiB

  prep_kernel<<<132, 256, 0, stream>>>(W0_rel, W0_root, Wt, Wl, Wv, WlT);
  gemm0_mfma<<<dim3(2, BATCH), 256, 0, stream>>>(
      flat, nodes, num_nodes, Wt, YT);
  fused_aggr<<<BATCH, 256, 0, stream>>>(YT, adj, num_nodes, b0, Z);
  gemm1_kernel<<<dim3(16, 4), 256, 0, stream>>>(Z, W1_rel, W1_root, b1, h1);
  head_kernel<<<BATCH, 256, 0, stream>>>(h1, WlT, bl, bv, out);
}

// Round 6
// 335.648 us; speedup vs baseline: 1.1154x; 1.1154x over previous
//
#include <hip/hip_runtime.h>
#include <hip/hip_bf16.h>
#include <cstdint>
#include <cstddef>

#define GS     128
#define OBS    1024
#define HSZ    256
#define OUTSZ  1024
#define NOUT   18
#define BATCH  256

typedef short  short8  __attribute__((ext_vector_type(8)));
typedef float  f32x4   __attribute__((ext_vector_type(4)));

__device__ __forceinline__ uint32_t f2bf_bits(float f) {
  uint32_t u = __builtin_bit_cast(uint32_t, f);
  return (u + 0x7fffu + ((u >> 16) & 1u)) >> 16;
}
__device__ __forceinline__ float bf_bits2f(uint32_t b) {
  return __builtin_bit_cast(float, b << 16);
}
__device__ __forceinline__ uint4 cvt8s(const float4 a, const float4 b) {
  float v[8] = {a.x, a.y, a.z, a.w, b.x, b.y, b.z, b.w};
  uint32_t h[8];
#pragma unroll
  for (int e = 0; e < 8; ++e) h[e] = f2bf_bits(v[e]);
  return make_uint4(h[0] | (h[1] << 16), h[2] | (h[3] << 16),
                    h[4] | (h[5] << 16), h[6] | (h[7] << 16));
}

// ---------------------------------------------------------------------------
// P0 (merged preps):
//  blk <128   : W0cat [1024][512] -> WtP[ks][col][32] bf16  (K-step packed:
//               element (k,col) lives at ((k>>5)*512 + col)*32 + (k&31))
//  blk 128-131: WlT[19][1024] (Wl^T rows 0..17, Wv row 18)
//  blk 132-163: W1bf[512][1024] bf16 of [W1_rel ; W1_root]
// ---------------------------------------------------------------------------
__global__ __launch_bounds__(256) void prep_kernel(
    const float* __restrict__ W0_rel, const float* __restrict__ W0_root,
    ushort* __restrict__ WtP, const float* __restrict__ Wl,
    const float* __restrict__ Wv, float* __restrict__ WlT,
    const float* __restrict__ W1_rel, const float* __restrict__ W1_root,
    ushort* __restrict__ W1bf)
{
  __shared__ float T[64][65];
  const int blk = blockIdx.x;
  const int t = threadIdx.x;
  if (blk < 128) {
    const int k0 = (blk & 15) * 64;
    const int n0 = (blk >> 4) * 64;
    for (int idx = t; idx < 4096; idx += 256) {
      const int r = idx >> 6, c = idx & 63;
      const int n = n0 + c;
      T[r][c] = (n < HSZ) ? W0_rel[(size_t)(k0 + r) * HSZ + n]
                          : W0_root[(size_t)(k0 + r) * HSZ + (n - HSZ)];
    }
    __syncthreads();
    for (int idx = t; idx < 4096; idx += 256) {
      const int r = idx >> 6, c = idx & 63;   // r: n-local, c: k-local
      const int kk = k0 + c;
      WtP[((size_t)((kk >> 5) * 512 + n0 + r)) * 32 + (kk & 31)] =
          (ushort)f2bf_bits(T[c][r]);
    }
  } else if (blk < 132) {
    const int o = (blk - 128) * 256 + t;
#pragma unroll
    for (int c = 0; c < NOUT; ++c)
      WlT[(size_t)c * OUTSZ + o] = Wl[(size_t)o * NOUT + c];
    WlT[(size_t)18 * OUTSZ + o] = Wv[o];
  } else {
    const int base = (blk - 132) * 16384;
    for (int it = 0; it < 64; ++it) {
      const int idx = base + it * 256 + t;
      const int k = idx >> 10, o = idx & 1023;
      const float v = (k < HSZ) ? W1_rel[(size_t)k * OUTSZ + o]
                                : W1_root[(size_t)(k - HSZ) * OUTSZ + o];
      W1bf[idx] = (ushort)f2bf_bits(v);
    }
  }
}

// ---------------------------------------------------------------------------
// K1: YT[b][h][k] bf16 (h in [0,256), k in [0,256)):
//   k<128 : (x @ W0_rel)^T [h][node k] ; k>=128: (x @ W0_root)^T [h][node]
// Grid (2, BATCH), block = 64 node-rows x all 512 cat-cols.
// A (nodes) staged via LDS (read once, cvt once). B fragments loaded DIRECTLY
// from L2 out of the packed WtP layout (lane-contiguous 16B), ping-pong
// prefetched one K-step ahead. Only A needs the barrier.
// ---------------------------------------------------------------------------
__global__ __launch_bounds__(256, 2) void gemm0_mfma(
    const float* __restrict__ flat, const float* __restrict__ nodes,
    const int* __restrict__ num_nodes, const ushort* __restrict__ WtP,
    ushort* __restrict__ YT)
{
  __shared__ ushort As[64][40];    // [node-row][k] (+8 pad)

  const int mh = blockIdx.x;       // node-row half
  const int b  = blockIdx.y;
  const int nb = num_nodes[b];
  const int t  = threadIdx.x;

  const int arow = t >> 2;
  const int akb  = (t & 3) * 8;    // 8 floats / 8 bf16 within the 32-k slice
  const int g = mh * 64 + arow;
  const float* xsrc = ((g == nb) ? (flat + (size_t)b * OBS)
                                 : (nodes + ((size_t)b * GS + g) * OBS)) + akb;

  const int wv = t >> 6;           // wave owns cat-cols [wv*128, wv*128+128)
  const int lane = t & 63;
  const int ln = lane & 15, q = lane >> 4;

  // B fragment pointer: (ks,jj) -> bptr + ks*16384 + jj*512
  const ushort* bptr = WtP + ((size_t)(wv * 128 + ln)) * 32 + q * 8;

  f32x4 acc[8][4] = {};

  float4 pa0 = *(const float4*)(xsrc);
  float4 pa1 = *(const float4*)(xsrc + 4);
  float4 qa0, qa1;

  short8 bha[8], bhb[8];
#pragma unroll
  for (int jj = 0; jj < 8; ++jj)
    bha[jj] = *(const short8*)(bptr + jj * 512);

  for (int ks = 0; ks < 32; ks += 2) {
    // ---- even step (uses bha) ----
    *(uint4*)&As[arow][akb] = cvt8s(pa0, pa1);
    __syncthreads();
    {
      const int kn = ks + 1;
      qa0 = *(const float4*)(xsrc + kn * 32);
      qa1 = *(const float4*)(xsrc + kn * 32 + 4);
      const ushort* bp = bptr + (size_t)kn * 16384;
#pragma unroll
      for (int jj = 0; jj < 8; ++jj)
        bhb[jj] = *(const short8*)(bp + jj * 512);
    }
    short8 ah[4];
#pragma unroll
    for (int ii = 0; ii < 4; ++ii)
      ah[ii] = *(const short8*)&As[ii * 16 + ln][q * 8];
#pragma unroll
    for (int jj = 0; jj < 8; ++jj)
#pragma unroll
      for (int ii = 0; ii < 4; ++ii)
        acc[jj][ii] = __builtin_amdgcn_mfma_f32_16x16x32_bf16(
            bha[jj], ah[ii], acc[jj][ii], 0, 0, 0);
    __syncthreads();

    // ---- odd step (uses bhb) ----
    *(uint4*)&As[arow][akb] = cvt8s(qa0, qa1);
    __syncthreads();
    if (ks + 2 < 32) {
      const int kn = ks + 2;
      pa0 = *(const float4*)(xsrc + kn * 32);
      pa1 = *(const float4*)(xsrc + kn * 32 + 4);
      const ushort* bp = bptr + (size_t)kn * 16384;
#pragma unroll
      for (int jj = 0; jj < 8; ++jj)
        bha[jj] = *(const short8*)(bp + jj * 512);
    }
#pragma unroll
    for (int ii = 0; ii < 4; ++ii)
      ah[ii] = *(const short8*)&As[ii * 16 + ln][q * 8];
#pragma unroll
    for (int jj = 0; jj < 8; ++jj)
#pragma unroll
      for (int ii = 0; ii < 4; ++ii)
        acc[jj][ii] = __builtin_amdgcn_mfma_f32_16x16x32_bf16(
            bhb[jj], ah[ii], acc[jj][ii], 0, 0, 0);
    __syncthreads();
  }

  // D row = cat-col (q*4+r within 16), D col = node (ln within 16)
#pragma unroll
  for (int jj = 0; jj < 8; ++jj) {
    const int hp = wv * 128 + jj * 16 + q * 4;
    const int kofs = (hp < 256) ? 0 : 128;
#pragma unroll
    for (int ii = 0; ii < 4; ++ii) {
      const int kidx = kofs + mh * 64 + ii * 16 + ln;
#pragma unroll
      for (int r = 0; r < 4; ++r) {
        const int h2 = (hp + r) & 255;
        YT[((size_t)b * 256 + h2) * 256 + kidx] =
            (ushort)f2bf_bits(acc[jj][ii][r]);
      }
    }
  }
}

// ---------------------------------------------------------------------------
// K2 (grid (2, BATCH), h-halves): masks -> MFMA P = A^T @ Yrel -> epilogue
// adds Yroot (identity part) + relu + masked sum.
//   Z[b][h]     = sum_{j in S} relu(b0+P[j][h]+Yroot[j][h])
//   Z[b][256+h] = value at j==n
// ---------------------------------------------------------------------------
__global__ __launch_bounds__(256, 2) void fused_aggr(
    const ushort* __restrict__ YT, const int* __restrict__ adj,
    const int* __restrict__ num_nodes, const float* __restrict__ b0,
    float* __restrict__ Z)
{
  __shared__ ushort   Ys[128][264];     // 66 KB: rows h-local, cols k 0..255
  __shared__ uint32_t rm[128][4];
  __shared__ uint32_t cmL[128][4];

  const int hh = blockIdx.x;            // h-half
  const int b  = blockIdx.y;
  const int n  = num_nodes[b];
  const int t  = threadIdx.x;
  const int wv = t >> 6, lane = t & 63;
  const int ln = lane & 15, q = lane >> 4;

  // stage YT[b] h-half -> LDS
  for (int it = 0; it < 16; ++it) {
    const int id = t + it * 256;
    const int row = id >> 5, c8 = (id & 31) * 8;
    *(uint4*)&Ys[row][c8] =
        *(const uint4*)&YT[((size_t)(b * 256 + hh * 128 + row)) * 256 + c8];
  }

  // masks
#pragma unroll 4
  for (int i = 0; i < 32; ++i) {
    const int k = wv * 32 + i;
    const int* arow = adj + ((size_t)b * GS + k) * GS;
    const unsigned long long m0 = __ballot(arow[lane] != 0);
    const unsigned long long m1 = __ballot(arow[64 + lane] != 0);
    if (lane == 0) {
      rm[k][0] = (uint32_t)m0; rm[k][1] = (uint32_t)(m0 >> 32);
      rm[k][2] = (uint32_t)m1; rm[k][3] = (uint32_t)(m1 >> 32);
    }
  }
  __syncthreads();
  if (t < 128) {
    uint32_t c0 = 0, c1 = 0, c2 = 0, c3 = 0;
    const int w = t >> 5, sh = t & 31;
#pragma unroll 8
    for (int k = 0; k < 128; ++k) {
      const uint32_t bit = (rm[k][w] >> sh) & 1u;
      if (k < 32)      c0 |= bit << k;
      else if (k < 64) c1 |= bit << (k - 32);
      else if (k < 96) c2 |= bit << (k - 64);
      else             c3 |= bit << (k - 96);
    }
    cmL[t][0] = c0; cmL[t][1] = c1; cmL[t][2] = c2; cmL[t][3] = c3;
  }
  __syncthreads();
  if (t == 0) {
    cmL[n][n >> 5] |= 1u << (n & 31);
    if (n > 0) {
      cmL[n - 1][n >> 5] |= 1u << (n & 31);
      cmL[n][(n - 1) >> 5] |= 1u << ((n - 1) & 31);
    }
  }
  __syncthreads();

  // MFMA: wave wv owns h-local [wv*32, wv*32+32); rel part only (k<128)
  f32x4 acc[8][2] = {};
  for (int ks = 0; ks < 4; ++ks) {
    short8 bf[2];
#pragma unroll
    for (int ht = 0; ht < 2; ++ht)
      bf[ht] = *(const short8*)&Ys[wv * 32 + ht * 16 + ln][ks * 32 + q * 8];
#pragma unroll
    for (int jt = 0; jt < 8; ++jt) {
      const uint32_t w = cmL[jt * 16 + ln][ks];
      const uint32_t byte = (w >> (q * 8)) & 0xFFu;
      short8 af;
#pragma unroll
      for (int i = 0; i < 8; ++i)
        af[i] = (short)(((byte >> i) & 1u) ? 0x3F80 : 0);
#pragma unroll
      for (int ht = 0; ht < 2; ++ht)
        acc[jt][ht] = __builtin_amdgcn_mfma_f32_16x16x32_bf16(
            af, bf[ht], acc[jt][ht], 0, 0, 0);
    }
  }

  // epilogue: add Yroot (identity part), relu, masked sums
  const uint32_t S0 = cmL[n][0], S1 = cmL[n][1], S2 = cmL[n][2], S3 = cmL[n][3];
  float bb[2];
#pragma unroll
  for (int ht = 0; ht < 2; ++ht) bb[ht] = b0[hh * 128 + wv * 32 + ht * 16 + ln];

  float asum[2] = {0.f, 0.f};
#pragma unroll
  for (int jt = 0; jt < 8; ++jt)
#pragma unroll
    for (int r = 0; r < 4; ++r) {
      const int j = jt * 16 + q * 4 + r;
      const uint32_t Sw = (j < 32) ? S0 : (j < 64) ? S1 : (j < 96) ? S2 : S3;
      const bool sj = (Sw >> (j & 31)) & 1u;
      const bool isn = (j == n);
#pragma unroll
      for (int ht = 0; ht < 2; ++ht) {
        const int hl = wv * 32 + ht * 16 + ln;
        const float yroot = bf_bits2f(Ys[hl][128 + j]);
        const float v = fmaxf(bb[ht] + yroot + acc[jt][ht][r], 0.f);
        if (sj) asum[ht] += v;
        if (isn) Z[(size_t)b * 512 + 256 + hh * 128 + hl] = v;
      }
    }

  // reduce over q-groups (lanes l, l+16, l+32, l+48)
#pragma unroll
  for (int ht = 0; ht < 2; ++ht) {
    float s = asum[ht];
    s += __shfl_down(s, 32);
    s += __shfl_down(s, 16);
    if (ln == lane)  // lanes 0..15 (q==0)
      Z[(size_t)b * 512 + hh * 128 + wv * 32 + ht * 16 + ln] = s;
  }
}

// ---------------------------------------------------------------------------
// K3 (fused, per batch): h1 = relu(Z[b] @ W1bf + b1) in registers,
// then logits/value via WlT + shuffle reduce.
// ---------------------------------------------------------------------------
__global__ __launch_bounds__(256) void gemm1_head(
    const float* __restrict__ Z, const ushort* __restrict__ W1bf,
    const float* __restrict__ b1, const float* __restrict__ WlT,
    const float* __restrict__ bl, const float* __restrict__ bv,
    float* __restrict__ out)
{
  __shared__ float Zl[512];
  __shared__ float pl[19][4];

  const int b = blockIdx.x;
  const int t = threadIdx.x;
  const int wv = t >> 6, lane = t & 63;
  const int o4 = t * 4;

  Zl[t]       = Z[(size_t)b * 512 + t];
  Zl[256 + t] = Z[(size_t)b * 512 + 256 + t];
  __syncthreads();

  float4 a = *(const float4*)&b1[o4];
  const ushort* wp = W1bf + o4;
#pragma unroll 8
  for (int k = 0; k < 512; ++k) {
    const ushort4 w4 = *(const ushort4*)(wp + (size_t)k * OUTSZ);
    const float s = Zl[k];
    a.x = fmaf(s, bf_bits2f(w4.x), a.x);
    a.y = fmaf(s, bf_bits2f(w4.y), a.y);
    a.z = fmaf(s, bf_bits2f(w4.z), a.z);
    a.w = fmaf(s, bf_bits2f(w4.w), a.w);
  }
  a.x = fmaxf(a.x, 0.f); a.y = fmaxf(a.y, 0.f);
  a.z = fmaxf(a.z, 0.f); a.w = fmaxf(a.w, 0.f);

  float p[19];
#pragma unroll
  for (int c = 0; c < 19; ++c) {
    const float4 w = *(const float4*)&WlT[(size_t)c * OUTSZ + o4];
    p[c] = a.x * w.x + a.y * w.y + a.z * w.z + a.w * w.w;
  }
#pragma unroll
  for (int c = 0; c < 19; ++c) {
    float v = p[c];
    v += __shfl_down(v, 32); v += __shfl_down(v, 16);
    v += __shfl_down(v, 8);  v += __shfl_down(v, 4);
    v += __shfl_down(v, 2);  v += __shfl_down(v, 1);
    if (lane == 0) pl[c][wv] = v;
  }
  __syncthreads();
  if (t < 19) {
    const float s = pl[t][0] + pl[t][1] + pl[t][2] + pl[t][3];
    if (t < NOUT) out[(size_t)b * NOUT + t] = s + bl[t];
    else          out[(size_t)BATCH * NOUT + b] = s + bv[0];
  }
}

// ---------------------------------------------------------------------------
extern "C" void kernel_launch(void* const* d_in, const int* in_sizes, int n_in,
                              void* d_out, int out_size, void* d_ws, size_t ws_size,
                              hipStream_t stream)
{
  const float* flat      = (const float*)d_in[0];
  const float* nodes     = (const float*)d_in[1];
  const int*   num_nodes = (const int*)  d_in[2];
  const int*   adj       = (const int*)  d_in[3];
  const float* W0_rel    = (const float*)d_in[5];
  const float* b0        = (const float*)d_in[6];
  const float* W0_root   = (const float*)d_in[7];
  const float* W1_rel    = (const float*)d_in[8];
  const float* b1        = (const float*)d_in[9];
  const float* W1_root   = (const float*)d_in[10];
  const float* Wl        = (const float*)d_in[11];
  const float* bl        = (const float*)d_in[12];
  const float* Wv        = (const float*)d_in[13];
  const float* bv        = (const float*)d_in[14];
  float* out = (float*)d_out;

  char* ws = (char*)d_ws;
  ushort* YT   = (ushort*)ws;  ws += (size_t)BATCH * 256 * 256 * 2;  // 32 MiB
  ushort* WtP  = (ushort*)ws;  ws += (size_t)512 * OBS * 2;          // 1 MiB
  float*  WlT  = (float*)ws;   ws += (size_t)19 * OUTSZ * 4;         // 76 KiB
  ushort* W1bf = (ushort*)ws;  ws += (size_t)512 * OUTSZ * 2;        // 1 MiB
  float*  Z    = (float*)ws;   ws += (size_t)BATCH * 512 * 4;        // 512 KiB

  prep_kernel<<<164, 256, 0, stream>>>(
      W0_rel, W0_root, WtP, Wl, Wv, WlT, W1_rel, W1_root, W1bf);
  gemm0_mfma<<<dim3(2, BATCH), 256, 0, stream>>>(
      flat, nodes, num_nodes, WtP, YT);
  fused_aggr<<<dim3(2, BATCH), 256, 0, stream>>>(YT, adj, num_nodes, b0, Z);
  gemm1_head<<<BATCH, 256, 0, stream>>>(Z, W1bf, b1, WlT, bl, bv, out);
}

// Round 7
// 318.331 us; speedup vs baseline: 1.1761x; 1.0544x over previous
//
#include <hip/hip_runtime.h>
#include <hip/hip_bf16.h>
#include <cstdint>
#include <cstddef>

#define GS     128
#define OBS    1024
#define HSZ    256
#define OUTSZ  1024
#define NOUT   18
#define BATCH  256

typedef short  short8  __attribute__((ext_vector_type(8)));
typedef float  f32x4   __attribute__((ext_vector_type(4)));

__device__ __forceinline__ uint32_t f2bf_bits(float f) {
  uint32_t u = __builtin_bit_cast(uint32_t, f);
  return (u + 0x7fffu + ((u >> 16) & 1u)) >> 16;
}
__device__ __forceinline__ float bf_bits2f(uint32_t b) {
  return __builtin_bit_cast(float, b << 16);
}
__device__ __forceinline__ uint4 cvt8s(const float4 a, const float4 b) {
  float v[8] = {a.x, a.y, a.z, a.w, b.x, b.y, b.z, b.w};
  uint32_t h[8];
#pragma unroll
  for (int e = 0; e < 8; ++e) h[e] = f2bf_bits(v[e]);
  return make_uint4(h[0] | (h[1] << 16), h[2] | (h[3] << 16),
                    h[4] | (h[5] << 16), h[6] | (h[7] << 16));
}

// ---------------------------------------------------------------------------
// P0 (merged preps):
//  blk <128   : W0cat [1024][512] -> WtP packed bf16:
//               element (k,col) at ((k>>5)*512 + col)*32 + (k&31)
//  blk 128-131: WlT[19][1024] (Wl^T rows 0..17, Wv row 18)
//  blk 132-163: W1bf[512][1024] bf16 of [W1_rel ; W1_root]
// ---------------------------------------------------------------------------
__global__ __launch_bounds__(256) void prep_kernel(
    const float* __restrict__ W0_rel, const float* __restrict__ W0_root,
    ushort* __restrict__ WtP, const float* __restrict__ Wl,
    const float* __restrict__ Wv, float* __restrict__ WlT,
    const float* __restrict__ W1_rel, const float* __restrict__ W1_root,
    ushort* __restrict__ W1bf)
{
  __shared__ float T[64][65];
  const int blk = blockIdx.x;
  const int t = threadIdx.x;
  if (blk < 128) {
    const int k0 = (blk & 15) * 64;
    const int n0 = (blk >> 4) * 64;
    for (int idx = t; idx < 4096; idx += 256) {
      const int r = idx >> 6, c = idx & 63;
      const int n = n0 + c;
      T[r][c] = (n < HSZ) ? W0_rel[(size_t)(k0 + r) * HSZ + n]
                          : W0_root[(size_t)(k0 + r) * HSZ + (n - HSZ)];
    }
    __syncthreads();
    for (int idx = t; idx < 4096; idx += 256) {
      const int r = idx >> 6, c = idx & 63;   // r: n-local, c: k-local
      const int kk = k0 + c;
      WtP[((size_t)((kk >> 5) * 512 + n0 + r)) * 32 + (kk & 31)] =
          (ushort)f2bf_bits(T[c][r]);
    }
  } else if (blk < 132) {
    const int o = (blk - 128) * 256 + t;
#pragma unroll
    for (int c = 0; c < NOUT; ++c)
      WlT[(size_t)c * OUTSZ + o] = Wl[(size_t)o * NOUT + c];
    WlT[(size_t)18 * OUTSZ + o] = Wv[o];
  } else {
    const int base = (blk - 132) * 16384;
    for (int it = 0; it < 64; ++it) {
      const int idx = base + it * 256 + t;
      const int k = idx >> 10, o = idx & 1023;
      const float v = (k < HSZ) ? W1_rel[(size_t)k * OUTSZ + o]
                                : W1_root[(size_t)(k - HSZ) * OUTSZ + o];
      W1bf[idx] = (ushort)f2bf_bits(v);
    }
  }
}

// ---------------------------------------------------------------------------
// MEGA kernel: one block per batch. Phases:
//  A: adjacency ballots -> row masks -> column masks cm (+forced entries)
//  B: gemm0: Ys[h][k] = bf16((x @ [W0_rel|W0_root])^T), entirely in LDS
//     (Ys[h][k<128] = Yrel[node k][h]; Ys[h][128+j] = Yroot[node j][h])
//  C: aggr: P = A^T @ Yrel via MFMA (A-frag from mask bits); epilogue adds
//     Yroot + b0, relu, masked sum -> a1s / rns in LDS
//  D: h1 = relu([a1|rn] @ W1bf + b1) in registers; logits/value via WlT
// ---------------------------------------------------------------------------
__global__ __launch_bounds__(256, 1) void mega_kernel(
    const float* __restrict__ flat, const float* __restrict__ nodes,
    const int* __restrict__ num_nodes, const int* __restrict__ adj,
    const float* __restrict__ b0, const ushort* __restrict__ WtP,
    const ushort* __restrict__ W1bf, const float* __restrict__ b1,
    const float* __restrict__ WlT, const float* __restrict__ bl,
    const float* __restrict__ bv, float* __restrict__ out)
{
  __shared__ ushort   Ys[256][264];   // 132 KB
  __shared__ ushort   As[128][40];    // 10 KB
  __shared__ uint32_t rm[128][4];
  __shared__ uint32_t cmL[128][4];
  __shared__ float    a1s[256];
  __shared__ float    rns[256];
  __shared__ float    pl[19][4];

  const int b  = blockIdx.x;
  const int nb = num_nodes[b];
  const int t  = threadIdx.x;
  const int wv = t >> 6, lane = t & 63;
  const int ln = lane & 15, q = lane >> 4;

  // ---------------- Phase A: masks ----------------
#pragma unroll 4
  for (int i = 0; i < 32; ++i) {
    const int k = wv * 32 + i;
    const int* arow = adj + ((size_t)b * GS + k) * GS;
    const unsigned long long m0 = __ballot(arow[lane] != 0);
    const unsigned long long m1 = __ballot(arow[64 + lane] != 0);
    if (lane == 0) {
      rm[k][0] = (uint32_t)m0; rm[k][1] = (uint32_t)(m0 >> 32);
      rm[k][2] = (uint32_t)m1; rm[k][3] = (uint32_t)(m1 >> 32);
    }
  }
  __syncthreads();
  if (t < 128) {
    uint32_t c0 = 0, c1 = 0, c2 = 0, c3 = 0;
    const int w = t >> 5, sh = t & 31;
#pragma unroll 8
    for (int k = 0; k < 128; ++k) {
      const uint32_t bit = (rm[k][w] >> sh) & 1u;
      if (k < 32)      c0 |= bit << k;
      else if (k < 64) c1 |= bit << (k - 32);
      else if (k < 96) c2 |= bit << (k - 64);
      else             c3 |= bit << (k - 96);
    }
    cmL[t][0] = c0; cmL[t][1] = c1; cmL[t][2] = c2; cmL[t][3] = c3;
  }
  __syncthreads();
  if (t == 0) {
    cmL[nb][nb >> 5] |= 1u << (nb & 31);
    if (nb > 0) {
      cmL[nb - 1][nb >> 5] |= 1u << (nb & 31);
      cmL[nb][(nb - 1) >> 5] |= 1u << ((nb - 1) & 31);
    }
  }

  // ---------------- Phase B: gemm0 into LDS ----------------
  // A staging: thread -> (row t>>1, 16 k's at (t&1)*16)
  const int arow2 = t >> 1;
  const int akb   = (t & 1) * 16;
  const float* xsrc = ((arow2 == nb) ? (flat + (size_t)b * OBS)
                                     : (nodes + ((size_t)b * GS + arow2) * OBS)) + akb;
  // B frags direct from L2 (packed layout): wave owns cat-cols [wv*128, +128)
  const ushort* bptr = WtP + ((size_t)(wv * 128 + ln)) * 32 + q * 8;

  f32x4 acc[8][8] = {};   // [jj: col-tile][ii: node-tile]

  float4 pa0 = *(const float4*)(xsrc);
  float4 pa1 = *(const float4*)(xsrc + 4);
  float4 pa2 = *(const float4*)(xsrc + 8);
  float4 pa3 = *(const float4*)(xsrc + 12);
  float4 qa0, qa1, qa2, qa3;

  short8 bha[8], bhb[8];
#pragma unroll
  for (int jj = 0; jj < 8; ++jj)
    bha[jj] = *(const short8*)(bptr + jj * 512);

  for (int ks = 0; ks < 32; ks += 2) {
    // even half-step (bha)
    *(uint4*)&As[arow2][akb]     = cvt8s(pa0, pa1);
    *(uint4*)&As[arow2][akb + 8] = cvt8s(pa2, pa3);
    {
      const int kn = (ks + 1) * 32;
      qa0 = *(const float4*)(xsrc + kn);
      qa1 = *(const float4*)(xsrc + kn + 4);
      qa2 = *(const float4*)(xsrc + kn + 8);
      qa3 = *(const float4*)(xsrc + kn + 12);
    }
    __syncthreads();
    {
      const ushort* bp = bptr + (size_t)(ks + 1) * 16384;
#pragma unroll
      for (int jj = 0; jj < 8; ++jj)
        bhb[jj] = *(const short8*)(bp + jj * 512);
    }
    short8 ah[8];
#pragma unroll
    for (int ii = 0; ii < 8; ++ii)
      ah[ii] = *(const short8*)&As[ii * 16 + ln][q * 8];
#pragma unroll
    for (int jj = 0; jj < 8; ++jj)
#pragma unroll
      for (int ii = 0; ii < 8; ++ii)
        acc[jj][ii] = __builtin_amdgcn_mfma_f32_16x16x32_bf16(
            bha[jj], ah[ii], acc[jj][ii], 0, 0, 0);
    __syncthreads();

    // odd half-step (bhb)
    *(uint4*)&As[arow2][akb]     = cvt8s(qa0, qa1);
    *(uint4*)&As[arow2][akb + 8] = cvt8s(qa2, qa3);
    if (ks + 2 < 32) {
      const int kn = (ks + 2) * 32;
      pa0 = *(const float4*)(xsrc + kn);
      pa1 = *(const float4*)(xsrc + kn + 4);
      pa2 = *(const float4*)(xsrc + kn + 8);
      pa3 = *(const float4*)(xsrc + kn + 12);
    }
    __syncthreads();
    if (ks + 2 < 32) {
      const ushort* bp = bptr + (size_t)(ks + 2) * 16384;
#pragma unroll
      for (int jj = 0; jj < 8; ++jj)
        bha[jj] = *(const short8*)(bp + jj * 512);
    }
#pragma unroll
    for (int ii = 0; ii < 8; ++ii)
      ah[ii] = *(const short8*)&As[ii * 16 + ln][q * 8];
#pragma unroll
    for (int jj = 0; jj < 8; ++jj)
#pragma unroll
      for (int ii = 0; ii < 8; ++ii)
        acc[jj][ii] = __builtin_amdgcn_mfma_f32_16x16x32_bf16(
            bhb[jj], ah[ii], acc[jj][ii], 0, 0, 0);
    __syncthreads();
  }

  // epilogue -> Ys (D row = cat-col q*4+r within 16; D col = node ln)
#pragma unroll
  for (int jj = 0; jj < 8; ++jj) {
    const int cat = wv * 128 + jj * 16 + q * 4;   // +r; side uniform per tile
    const int h   = cat & 255;
    const int kof = (cat < 256) ? 0 : 128;
#pragma unroll
    for (int ii = 0; ii < 8; ++ii) {
      const int kk = kof + ii * 16 + ln;
#pragma unroll
      for (int r = 0; r < 4; ++r)
        Ys[h + r][kk] = (ushort)f2bf_bits(acc[jj][ii][r]);
    }
  }
  __syncthreads();

  // ---------------- Phase C: aggregation ----------------
  // wave wv owns h in [wv*64, +64)
  f32x4 acc2[8][4] = {};
  for (int ks = 0; ks < 4; ++ks) {
    short8 bf[4];
#pragma unroll
    for (int ht = 0; ht < 4; ++ht)
      bf[ht] = *(const short8*)&Ys[wv * 64 + ht * 16 + ln][ks * 32 + q * 8];
#pragma unroll
    for (int jt = 0; jt < 8; ++jt) {
      const uint32_t w = cmL[jt * 16 + ln][ks];
      const uint32_t byte = (w >> (q * 8)) & 0xFFu;
      short8 af;
#pragma unroll
      for (int i = 0; i < 8; ++i)
        af[i] = (short)(((byte >> i) & 1u) ? 0x3F80 : 0);
#pragma unroll
      for (int ht = 0; ht < 4; ++ht)
        acc2[jt][ht] = __builtin_amdgcn_mfma_f32_16x16x32_bf16(
            af, bf[ht], acc2[jt][ht], 0, 0, 0);
    }
  }

  const uint32_t S0 = cmL[nb][0], S1 = cmL[nb][1],
                 S2 = cmL[nb][2], S3 = cmL[nb][3];
  float bb[4];
#pragma unroll
  for (int ht = 0; ht < 4; ++ht) bb[ht] = b0[wv * 64 + ht * 16 + ln];

  float asum[4] = {0.f, 0.f, 0.f, 0.f};
#pragma unroll
  for (int jt = 0; jt < 8; ++jt)
#pragma unroll
    for (int r = 0; r < 4; ++r) {
      const int j = jt * 16 + q * 4 + r;
      const uint32_t Sw = (j < 32) ? S0 : (j < 64) ? S1 : (j < 96) ? S2 : S3;
      const bool sj = (Sw >> (j & 31)) & 1u;
      const bool isn = (j == nb);
#pragma unroll
      for (int ht = 0; ht < 4; ++ht) {
        const int hl = wv * 64 + ht * 16 + ln;
        const float yroot = bf_bits2f(Ys[hl][128 + j]);
        const float v = fmaxf(bb[ht] + yroot + acc2[jt][ht][r], 0.f);
        if (sj) asum[ht] += v;
        if (isn) rns[hl] = v;
      }
    }
#pragma unroll
  for (int ht = 0; ht < 4; ++ht) {
    float s = asum[ht];
    s += __shfl_down(s, 32);
    s += __shfl_down(s, 16);
    if (q == 0) a1s[wv * 64 + ht * 16 + ln] = s;
  }
  __syncthreads();

  // ---------------- Phase D: gemm1 + head ----------------
  const int o4 = t * 4;
  float4 a = *(const float4*)&b1[o4];
  const ushort* wp = W1bf + o4;
#pragma unroll 8
  for (int k = 0; k < 256; ++k) {
    const ushort4 w4 = *(const ushort4*)(wp + (size_t)k * OUTSZ);
    const float s = a1s[k];
    a.x = fmaf(s, bf_bits2f(w4.x), a.x);
    a.y = fmaf(s, bf_bits2f(w4.y), a.y);
    a.z = fmaf(s, bf_bits2f(w4.z), a.z);
    a.w = fmaf(s, bf_bits2f(w4.w), a.w);
  }
#pragma unroll 8
  for (int k = 0; k < 256; ++k) {
    const ushort4 w4 = *(const ushort4*)(wp + (size_t)(256 + k) * OUTSZ);
    const float s = rns[k];
    a.x = fmaf(s, bf_bits2f(w4.x), a.x);
    a.y = fmaf(s, bf_bits2f(w4.y), a.y);
    a.z = fmaf(s, bf_bits2f(w4.z), a.z);
    a.w = fmaf(s, bf_bits2f(w4.w), a.w);
  }
  a.x = fmaxf(a.x, 0.f); a.y = fmaxf(a.y, 0.f);
  a.z = fmaxf(a.z, 0.f); a.w = fmaxf(a.w, 0.f);

  float p[19];
#pragma unroll
  for (int c = 0; c < 19; ++c) {
    const float4 w = *(const float4*)&WlT[(size_t)c * OUTSZ + o4];
    p[c] = a.x * w.x + a.y * w.y + a.z * w.z + a.w * w.w;
  }
#pragma unroll
  for (int c = 0; c < 19; ++c) {
    float v = p[c];
    v += __shfl_down(v, 32); v += __shfl_down(v, 16);
    v += __shfl_down(v, 8);  v += __shfl_down(v, 4);
    v += __shfl_down(v, 2);  v += __shfl_down(v, 1);
    if (lane == 0) pl[c][wv] = v;
  }
  __syncthreads();
  if (t < 19) {
    const float s = pl[t][0] + pl[t][1] + pl[t][2] + pl[t][3];
    if (t < NOUT) out[(size_t)b * NOUT + t] = s + bl[t];
    else          out[(size_t)BATCH * NOUT + b] = s + bv[0];
  }
}

// ---------------------------------------------------------------------------
extern "C" void kernel_launch(void* const* d_in, const int* in_sizes, int n_in,
                              void* d_out, int out_size, void* d_ws, size_t ws_size,
                              hipStream_t stream)
{
  const float* flat      = (const float*)d_in[0];
  const float* nodes     = (const float*)d_in[1];
  const int*   num_nodes = (const int*)  d_in[2];
  const int*   adj       = (const int*)  d_in[3];
  const float* W0_rel    = (const float*)d_in[5];
  const float* b0        = (const float*)d_in[6];
  const float* W0_root   = (const float*)d_in[7];
  const float* W1_rel    = (const float*)d_in[8];
  const float* b1        = (const float*)d_in[9];
  const float* W1_root   = (const float*)d_in[10];
  const float* Wl        = (const float*)d_in[11];
  const float* bl        = (const float*)d_in[12];
  const float* Wv        = (const float*)d_in[13];
  const float* bv        = (const float*)d_in[14];
  float* out = (float*)d_out;

  char* ws = (char*)d_ws;
  ushort* WtP  = (ushort*)ws;  ws += (size_t)512 * OBS * 2;   // 1 MiB
  float*  WlT  = (float*)ws;   ws += (size_t)19 * OUTSZ * 4;  // 76 KiB
  ushort* W1bf = (ushort*)ws;  ws += (size_t)512 * OUTSZ * 2; // 1 MiB

  prep_kernel<<<164, 256, 0, stream>>>(
      W0_rel, W0_root, WtP, Wl, Wv, WlT, W1_rel, W1_root, W1bf);
  mega_kernel<<<BATCH, 256, 0, stream>>>(
      flat, nodes, num_nodes, adj, b0, WtP, W1bf, b1, WlT, bl, bv, out);
}